// Round 2
// baseline (295.764 us; speedup 1.0000x reference)
//
#include <hip/hip_runtime.h>
#include <hip/hip_fp16.h>

// TriMul (outgoing) pipeline, MI355X gfx950.
// Stages:
//  K0: repack weights [Wp|Wg|Wgate] -> Wt[c][l] fp16  (576 x 64)
//  K1: LayerNorm(d=64) of z -> h fp16 [262144][64]   (h aliased into omid region)
//  K2: proj GEMM h @ Wt^T with fused sigmoid gating:
//        a_t[c][row], b_t[c][row] fp16 (channel-major for einsum), g_out[row][64] fp16
//  K3: batched einsum: for c in 0..127: C_c = A_c * B_c^T (512x512x512), MFMA 16x16x32 f16
//        out_mid[c][i*512+j] fp16  (overwrites h, which is dead by then)
//  K4: LayerNorm(128) + @Wout(128x64) + * g_out -> out fp32
//
// Workspace budget: 131072 (Wt) + 2*67,108,864 (a_t,b_t) + 33,554,432 (gout)
//                   + 67,108,864 (omid/h) = 235,012,096 B ~= 224 MiB  (< 256 MiB)

typedef _Float16 half_t;
typedef _Float16 f16x8 __attribute__((ext_vector_type(8)));
typedef float f32x4 __attribute__((ext_vector_type(4)));

#define NSEQ 512
#define DIM 64
#define HID 128
#define ROWS (NSEQ * NSEQ)   // 262144

// ---------------------------------------------------------------- K0: weights
__global__ void k_prep_w(const float* __restrict__ Wp, const float* __restrict__ Wg,
                         const float* __restrict__ Wgate, half_t* __restrict__ Wt) {
    int idx = blockIdx.x * 256 + threadIdx.x;     // over 576*64
    if (idx >= 576 * 64) return;
    int c = idx >> 6, l = idx & 63;
    float v;
    if (c < 256)       v = Wp[l * 256 + c];
    else if (c < 512)  v = Wg[l * 256 + (c - 256)];
    else               v = Wgate[l * 64 + (c - 512)];
    Wt[idx] = (half_t)v;
}

// ---------------------------------------------------------------- K1: LN(d=64)
__global__ __launch_bounds__(256) void k_ln_in(const float* __restrict__ z,
                                               const float* __restrict__ w,
                                               const float* __restrict__ b,
                                               half_t* __restrict__ h) {
    int row = blockIdx.x * 4 + (threadIdx.x >> 6);
    int lane = threadIdx.x & 63;
    float x = z[(size_t)row * 64 + lane];
    float s = x, s2 = x * x;
    #pragma unroll
    for (int off = 32; off; off >>= 1) {
        s  += __shfl_xor(s,  off, 64);
        s2 += __shfl_xor(s2, off, 64);
    }
    float mu = s * (1.f / 64.f);
    float var = s2 * (1.f / 64.f) - mu * mu;
    float rs = rsqrtf(var + 1e-5f);
    float hv = (x - mu) * rs * w[lane] + b[lane];
    h[(size_t)row * 64 + lane] = (half_t)hv;
}

// ---------------------------------------------------------------- K2: projections
// grid (4096, 2): x = 64-row block, y = channel half (0 -> a + gate[0..31], 1 -> b + gate[32..63])
__global__ __launch_bounds__(256) void k_proj(const half_t* __restrict__ h,
                                              const half_t* __restrict__ Wt,
                                              half_t* __restrict__ a_t,
                                              half_t* __restrict__ b_t,
                                              half_t* __restrict__ g_out) {
    __shared__ half_t Wl[288 * 64];        // 36 KB, swizzled rows of 128B
    __shared__ half_t hl[64 * 64];         // 8 KB, swizzled
    __shared__ half_t tscr[4][16][20];     // per-wave transpose scratch

    int t = threadIdx.x;
    int ch = blockIdx.y;
    int r0 = blockIdx.x * 64;

    // stage weights: 288 rows x 8 chunks of 16B
    #pragma unroll
    for (int it = 0; it < 9; ++it) {
        int chunk = it * 256 + t;          // 2304 total
        int lr = chunk >> 3, co = chunk & 7;
        int grow;
        if (lr < 128)      grow = ch * 128 + lr;               // Wp cols
        else if (lr < 256) grow = 256 + ch * 128 + (lr - 128); // Wg cols
        else               grow = 512 + ch * 32 + (lr - 256);  // Wgate cols
        uint4 v = *(const uint4*)(Wt + (size_t)grow * 64 + co * 8);
        int boff = lr * 128 + ((co * 16) ^ ((lr & 7) << 4));
        *(uint4*)((char*)Wl + boff) = v;
    }
    // stage h tile: 64 rows
    #pragma unroll
    for (int it = 0; it < 2; ++it) {
        int chunk = it * 256 + t;          // 512 total
        int lr = chunk >> 3, co = chunk & 7;
        uint4 v = *(const uint4*)(h + (size_t)(r0 + lr) * 64 + co * 8);
        int boff = lr * 128 + ((co * 16) ^ ((lr & 7) << 4));
        *(uint4*)((char*)hl + boff) = v;
    }
    __syncthreads();

    int wid = t >> 6, lane = t & 63;
    int m = lane & 15, g = lane >> 4;

    // A fragments for this wave's 16-row strip (held across all col tiles)
    f16x8 af[2];
    {
        int lrow = wid * 16 + m;
        #pragma unroll
        for (int ks = 0; ks < 2; ++ks) {
            int kb = (ks * 32 + g * 8) * 2;
            af[ks] = *(const f16x8*)((char*)hl + lrow * 128 + (kb ^ ((lrow & 7) << 4)));
        }
    }
    int growbase = r0 + wid * 16;
    half_t* dst = (ch == 0) ? a_t : b_t;

    // p/g pair tiles -> pg = p * sigmoid(g)
    for (int pt = 0; pt < 8; ++pt) {
        f32x4 accp = {0.f, 0.f, 0.f, 0.f}, accg = {0.f, 0.f, 0.f, 0.f};
        #pragma unroll
        for (int ks = 0; ks < 2; ++ks) {
            int kb = (ks * 32 + g * 8) * 2;
            int lrp = pt * 16 + m;
            f16x8 bp = *(const f16x8*)((char*)Wl + lrp * 128 + (kb ^ ((lrp & 7) << 4)));
            int lrg = 128 + pt * 16 + m;
            f16x8 bg = *(const f16x8*)((char*)Wl + lrg * 128 + (kb ^ ((lrg & 7) << 4)));
            accp = __builtin_amdgcn_mfma_f32_16x16x32_f16(af[ks], bp, accp, 0, 0, 0);
            accg = __builtin_amdgcn_mfma_f32_16x16x32_f16(af[ks], bg, accg, 0, 0, 0);
        }
        #pragma unroll
        for (int r = 0; r < 4; ++r) {
            float p = accp[r], gg = accg[r];
            float pg = p * (1.f / (1.f + __expf(-gg)));
            tscr[wid][m][g * 4 + r] = (half_t)pg;   // [chan][row16]
        }
        // ensure the LDS stores above are emitted and complete before the
        // cross-lane read below (same-wave DS ops are in-order; this pins
        // the compiler ordering and drains the DS queue)
        asm volatile("s_waitcnt lgkmcnt(0)" ::: "memory");
        __builtin_amdgcn_wave_barrier();
        // write 16 rows per channel, 8B per lane (4 lanes/channel)
        int c16 = lane >> 2, rq = lane & 3;
        uint2 v = *(const uint2*)&tscr[wid][c16][rq * 4];
        int cglob = pt * 16 + c16;
        *(uint2*)(dst + (size_t)cglob * ROWS + growbase + rq * 4) = v;
        asm volatile("s_waitcnt lgkmcnt(0)" ::: "memory");
        __builtin_amdgcn_wave_barrier();
    }

    // gate tiles -> g_out[row][och] = sigmoid(h @ Wgate)
    for (int gt = 0; gt < 2; ++gt) {
        f32x4 acc = {0.f, 0.f, 0.f, 0.f};
        #pragma unroll
        for (int ks = 0; ks < 2; ++ks) {
            int kb = (ks * 32 + g * 8) * 2;
            int lr = 256 + gt * 16 + m;
            f16x8 bb = *(const f16x8*)((char*)Wl + lr * 128 + (kb ^ ((lr & 7) << 4)));
            acc = __builtin_amdgcn_mfma_f32_16x16x32_f16(af[ks], bb, acc, 0, 0, 0);
        }
        int och = ch * 32 + gt * 16 + m;
        #pragma unroll
        for (int r = 0; r < 4; ++r) {
            float og = 1.f / (1.f + __expf(-acc[r]));
            int grow = growbase + g * 4 + r;
            g_out[(size_t)grow * 64 + och] = (half_t)og;
        }
    }
}

// ---------------------------------------------------------------- K3: batched einsum
// grid (16, 128): x = 4x4 (i,j) 128-tiles, y = channel c
__global__ __launch_bounds__(256) void k_einsum(const half_t* __restrict__ a_t,
                                                const half_t* __restrict__ b_t,
                                                half_t* __restrict__ out_mid) {
    __shared__ half_t Al[128 * 64];   // 16 KB
    __shared__ half_t Bl[128 * 64];   // 16 KB

    int t = threadIdx.x;
    int c = blockIdx.y;
    int i0 = (blockIdx.x & 3) * 128, j0 = (blockIdx.x >> 2) * 128;
    const half_t* A = a_t + (size_t)c * ROWS;   // [i][k]
    const half_t* B = b_t + (size_t)c * ROWS;   // [j][k]

    int wid = t >> 6, lane = t & 63;
    int m = lane & 15, g = lane >> 4;
    int wrb = (wid & 1) * 64, wcb = (wid >> 1) * 64;

    f32x4 acc[4][4] = {};

    for (int kt = 0; kt < 8; ++kt) {
        __syncthreads();
        #pragma unroll
        for (int it = 0; it < 4; ++it) {
            int chunk = it * 256 + t;          // 1024 per operand
            int lr = chunk >> 3, co = chunk & 7;
            uint4 va = *(const uint4*)(A + (size_t)(i0 + lr) * 512 + kt * 64 + co * 8);
            uint4 vb = *(const uint4*)(B + (size_t)(j0 + lr) * 512 + kt * 64 + co * 8);
            int boff = lr * 128 + ((co * 16) ^ ((lr & 7) << 4));
            *(uint4*)((char*)Al + boff) = va;
            *(uint4*)((char*)Bl + boff) = vb;
        }
        __syncthreads();

        #pragma unroll
        for (int ks = 0; ks < 2; ++ks) {
            int kb = (ks * 32 + g * 8) * 2;
            f16x8 af[4], bf[4];
            #pragma unroll
            for (int mi = 0; mi < 4; ++mi) {
                int lrow = wrb + mi * 16 + m;
                af[mi] = *(const f16x8*)((char*)Al + lrow * 128 + (kb ^ ((lrow & 7) << 4)));
            }
            #pragma unroll
            for (int ni = 0; ni < 4; ++ni) {
                int lrow = wcb + ni * 16 + m;
                bf[ni] = *(const f16x8*)((char*)Bl + lrow * 128 + (kb ^ ((lrow & 7) << 4)));
            }
            #pragma unroll
            for (int mi = 0; mi < 4; ++mi)
                #pragma unroll
                for (int ni = 0; ni < 4; ++ni)
                    acc[mi][ni] = __builtin_amdgcn_mfma_f32_16x16x32_f16(af[mi], bf[ni], acc[mi][ni], 0, 0, 0);
        }
    }

    half_t* O = out_mid + (size_t)c * ROWS;   // [i*512 + j]
    #pragma unroll
    for (int mi = 0; mi < 4; ++mi) {
        #pragma unroll
        for (int ni = 0; ni < 4; ++ni) {
            int row = i0 + wrb + mi * 16 + g * 4;
            int col = j0 + wcb + ni * 16 + m;
            #pragma unroll
            for (int r = 0; r < 4; ++r)
                O[(size_t)(row + r) * 512 + col] = (half_t)acc[mi][ni][r];
        }
    }
}

// ---------------------------------------------------------------- K4: LN(128) + Wout + gate
// grid 4096: 64 positions per block
__global__ __launch_bounds__(256) void k_final(const half_t* __restrict__ out_mid,
                                               const float* __restrict__ w,
                                               const float* __restrict__ bb,
                                               const float* __restrict__ Wout,
                                               const half_t* __restrict__ g_out,
                                               float* __restrict__ out) {
    __shared__ half_t mid[128 * 64];    // [c][p] 16 KB
    __shared__ half_t gl[64 * 66];      // [p][och] padded, 8.25 KB
    __shared__ float  wl[128 * 64];     // Wout 32 KB

    int t = threadIdx.x;
    int pos0 = blockIdx.x * 64;

    #pragma unroll
    for (int it = 0; it < 4; ++it) {
        int chunk = it * 256 + t;       // 1024
        int cc = chunk >> 3, co = chunk & 7;
        uint4 v = *(const uint4*)(out_mid + (size_t)cc * ROWS + pos0 + co * 8);
        *(uint4*)((char*)mid + cc * 128 + co * 16) = v;
    }
    #pragma unroll
    for (int it = 0; it < 2; ++it) {
        int chunk = it * 256 + t;       // 512
        int p = chunk >> 3, co = chunk & 7;
        uint4 v = *(const uint4*)(g_out + (size_t)(pos0 + p) * 64 + co * 8);
        *(uint4*)((char*)gl + p * 132 + co * 16) = v;
    }
    #pragma unroll
    for (int it = 0; it < 8; ++it) {
        int chunk = it * 256 + t;       // 2048 x 16B
        *(uint4*)((char*)wl + chunk * 16) = *(const uint4*)(Wout + chunk * 4);
    }
    __syncthreads();

    int p = t & 63, ob = (t >> 6) * 16;

    float s = 0.f, s2 = 0.f;
    for (int cc = 0; cc < 128; ++cc) {
        float v = (float)mid[cc * 64 + p];
        s += v; s2 += v * v;
    }
    float mu = s * (1.f / 128.f);
    float var = s2 * (1.f / 128.f) - mu * mu;
    float rs = rsqrtf(var + 1e-5f);

    float acc[16] = {};
    for (int cc = 0; cc < 128; ++cc) {
        float nv = ((float)mid[cc * 64 + p] - mu) * rs * w[cc] + bb[cc];
        #pragma unroll
        for (int o4 = 0; o4 < 4; ++o4) {
            f32x4 wv = *(const f32x4*)&wl[cc * 64 + ob + o4 * 4];
            acc[o4 * 4 + 0] += nv * wv[0];
            acc[o4 * 4 + 1] += nv * wv[1];
            acc[o4 * 4 + 2] += nv * wv[2];
            acc[o4 * 4 + 3] += nv * wv[3];
        }
    }

    float* dst = out + (size_t)(pos0 + p) * 64 + ob;
    #pragma unroll
    for (int o4 = 0; o4 < 4; ++o4) {
        f32x4 v;
        #pragma unroll
        for (int j = 0; j < 4; ++j) {
            float gv = (float)gl[p * 66 + ob + o4 * 4 + j];
            v[j] = acc[o4 * 4 + j] * gv;
        }
        *(f32x4*)(dst + o4 * 4) = v;
    }
}

// ---------------------------------------------------------------- launch
extern "C" void kernel_launch(void* const* d_in, const int* in_sizes, int n_in,
                              void* d_out, int out_size, void* d_ws, size_t ws_size,
                              hipStream_t stream) {
    const float* z        = (const float*)d_in[0];
    const float* ln_in_w  = (const float*)d_in[1];
    const float* ln_in_b  = (const float*)d_in[2];
    const float* Wp       = (const float*)d_in[3];
    const float* Wg       = (const float*)d_in[4];
    const float* ln_out_w = (const float*)d_in[5];
    const float* ln_out_b = (const float*)d_in[6];
    const float* Wout     = (const float*)d_in[7];
    const float* Wgate    = (const float*)d_in[8];
    float* out = (float*)d_out;

    // ws layout (235,012,096 B total):
    //   [0, 128K)           Wt
    //   [128K, +67MB)       a_t
    //   [.., +67MB)         b_t
    //   [.., +33.5MB)       gout
    //   [.., +67MB)         omid   (h aliases its first 33.5MB; dead before K3)
    char* wsb = (char*)d_ws;
    half_t* Wt   = (half_t*)wsb;
    half_t* a_t  = (half_t*)(wsb + 131072);
    half_t* b_t  = a_t + (size_t)HID * ROWS;
    half_t* gout = b_t + (size_t)HID * ROWS;
    half_t* omid = gout + (size_t)ROWS * 64;
    half_t* h    = omid;   // aliased: h consumed by K2, omid produced by K3

    k_prep_w<<<dim3(144), dim3(256), 0, stream>>>(Wp, Wg, Wgate, Wt);
    k_ln_in<<<dim3(ROWS / 4), dim3(256), 0, stream>>>(z, ln_in_w, ln_in_b, h);
    k_proj<<<dim3(ROWS / 64, 2), dim3(256), 0, stream>>>(h, Wt, a_t, b_t, gout);
    k_einsum<<<dim3(16, 128), dim3(256), 0, stream>>>(a_t, b_t, omid);
    k_final<<<dim3(ROWS / 64), dim3(256), 0, stream>>>(omid, ln_out_w, ln_out_b, Wout, gout, out);
}

// Round 4
// 209.785 us; speedup vs baseline: 1.4098x; 1.4098x over previous
//
#include <hip/hip_runtime.h>
#include <hip/hip_fp16.h>

// TriMul (outgoing) pipeline, MI355X gfx950.
//  K0: repack weights -> Wt[576][64] fp16; W1t[o][c]=ln_w[c]*Wout[c][o] fp16;
//      s1[o]=sum_c ln_w*Wout, s2[o]=sum_c ln_b*Wout (LN folded into final GEMM)
//  K1: LayerNorm(d=64) of z -> h fp16 [262144][64]   (h aliased into omid region)
//  K2: proj GEMM h @ Wt^T, fused sigmoid gating -> a_t/b_t [c][row] fp16, g_out fp16
//  K3: batched einsum per channel: C_c = A_c * B_c^T, 256x256 tiles, XCD-grouped
//  K4: stats + MFMA (raw mid @ W1) + affine LN correction + gate -> out fp32

typedef _Float16 half_t;
typedef _Float16 f16x8 __attribute__((ext_vector_type(8)));
typedef float f32x4 __attribute__((ext_vector_type(4)));

#define NSEQ 512
#define HID 128
#define ROWS (NSEQ * NSEQ)   // 262144

// ---------------------------------------------------------------- K0: weights
__global__ void k_prep_w(const float* __restrict__ Wp, const float* __restrict__ Wg,
                         const float* __restrict__ Wgate,
                         const float* __restrict__ ln_out_w, const float* __restrict__ ln_out_b,
                         const float* __restrict__ Wout,
                         half_t* __restrict__ Wt, half_t* __restrict__ W1t,
                         float* __restrict__ s1, float* __restrict__ s2) {
    int bid = blockIdx.x, t = threadIdx.x;
    if (bid < 144) {
        int idx = bid * 256 + t;                 // over 576*64
        int c = idx >> 6, l = idx & 63;
        float v;
        if (c < 256)       v = Wp[l * 256 + c];
        else if (c < 512)  v = Wg[l * 256 + (c - 256)];
        else               v = Wgate[l * 64 + (c - 512)];
        Wt[idx] = (half_t)v;
    } else {
        // W1t[o][c] = ln_out_w[c] * Wout[c][o]   (64 x 128)
        #pragma unroll
        for (int i = 0; i < 32; ++i) {
            int idx = t * 32 + i;                // 8192
            int o = idx >> 7, c = idx & 127;
            W1t[idx] = (half_t)(ln_out_w[c] * Wout[c * 64 + o]);
        }
        if (t < 64) {
            float a1 = 0.f, a2 = 0.f;
            for (int c = 0; c < 128; ++c) {
                float wo = Wout[c * 64 + t];
                a1 += ln_out_w[c] * wo;
                a2 += ln_out_b[c] * wo;
            }
            s1[t] = a1; s2[t] = a2;
        }
    }
}

// ---------------------------------------------------------------- K1: LN(d=64)
__global__ __launch_bounds__(256) void k_ln_in(const float* __restrict__ z,
                                               const float* __restrict__ w,
                                               const float* __restrict__ b,
                                               half_t* __restrict__ h) {
    int row = blockIdx.x * 4 + (threadIdx.x >> 6);
    int lane = threadIdx.x & 63;
    float x = z[(size_t)row * 64 + lane];
    float s = x, s2 = x * x;
    #pragma unroll
    for (int off = 32; off; off >>= 1) {
        s  += __shfl_xor(s,  off, 64);
        s2 += __shfl_xor(s2, off, 64);
    }
    float mu = s * (1.f / 64.f);
    float var = s2 * (1.f / 64.f) - mu * mu;
    float rs = rsqrtf(var + 1e-5f);
    float hv = (x - mu) * rs * w[lane] + b[lane];
    h[(size_t)row * 64 + lane] = (half_t)hv;
}

// ---------------------------------------------------------------- K2: projections
// grid (4096, 2): x = 64-row block, y = half (0 -> a + gate[0..31], 1 -> b + gate[32..63])
__global__ __launch_bounds__(256) void k_proj(const half_t* __restrict__ h,
                                              const half_t* __restrict__ Wt,
                                              half_t* __restrict__ a_t,
                                              half_t* __restrict__ b_t,
                                              half_t* __restrict__ g_out) {
    __shared__ half_t Wl[288 * 64];        // 36 KB, swizzled rows of 128B
    __shared__ half_t hl[64 * 64];         // 8 KB, swizzled
    __shared__ half_t pgl[128 * 72];       // 18 KB, [c][row] padded stride 72

    int t = threadIdx.x;
    int ch = blockIdx.y;
    int r0 = blockIdx.x * 64;

    // stage weights: 288 rows x 8 chunks of 16B
    #pragma unroll
    for (int it = 0; it < 9; ++it) {
        int chunk = it * 256 + t;          // 2304 total
        int lr = chunk >> 3, co = chunk & 7;
        int grow;
        if (lr < 128)      grow = ch * 128 + lr;               // Wp cols
        else if (lr < 256) grow = 256 + ch * 128 + (lr - 128); // Wg cols
        else               grow = 512 + ch * 32 + (lr - 256);  // Wgate cols
        uint4 v = *(const uint4*)(Wt + (size_t)grow * 64 + co * 8);
        int boff = lr * 128 + ((co * 16) ^ ((lr & 7) << 4));
        *(uint4*)((char*)Wl + boff) = v;
    }
    // stage h tile: 64 rows
    #pragma unroll
    for (int it = 0; it < 2; ++it) {
        int chunk = it * 256 + t;          // 512 total
        int lr = chunk >> 3, co = chunk & 7;
        uint4 v = *(const uint4*)(h + (size_t)(r0 + lr) * 64 + co * 8);
        int boff = lr * 128 + ((co * 16) ^ ((lr & 7) << 4));
        *(uint4*)((char*)hl + boff) = v;
    }
    __syncthreads();

    int wid = t >> 6, lane = t & 63;
    int m = lane & 15, g = lane >> 4;

    // A fragments for this wave's 16-row strip
    f16x8 af[2];
    {
        int lrow = wid * 16 + m;
        #pragma unroll
        for (int ks = 0; ks < 2; ++ks) {
            int kb = (ks * 32 + g * 8) * 2;
            af[ks] = *(const f16x8*)((char*)hl + lrow * 128 + (kb ^ ((lrow & 7) << 4)));
        }
    }
    int growbase = r0 + wid * 16;
    half_t* dst = (ch == 0) ? a_t : b_t;

    // p/g pair tiles -> pg = p * sigmoid(g) -> pgl[c][row]
    for (int pt = 0; pt < 8; ++pt) {
        f32x4 accp = {0.f, 0.f, 0.f, 0.f}, accg = {0.f, 0.f, 0.f, 0.f};
        #pragma unroll
        for (int ks = 0; ks < 2; ++ks) {
            int kb = (ks * 32 + g * 8) * 2;
            int lrp = pt * 16 + m;
            f16x8 bp = *(const f16x8*)((char*)Wl + lrp * 128 + (kb ^ ((lrp & 7) << 4)));
            int lrg = 128 + pt * 16 + m;
            f16x8 bg = *(const f16x8*)((char*)Wl + lrg * 128 + (kb ^ ((lrg & 7) << 4)));
            accp = __builtin_amdgcn_mfma_f32_16x16x32_f16(af[ks], bp, accp, 0, 0, 0);
            accg = __builtin_amdgcn_mfma_f32_16x16x32_f16(af[ks], bg, accg, 0, 0, 0);
        }
        #pragma unroll
        for (int r = 0; r < 4; ++r) {
            float p = accp[r], gg = accg[r];
            float pg = p * (1.f / (1.f + __expf(-gg)));
            pgl[(pt * 16 + m) * 72 + (wid * 16 + g * 4 + r)] = (half_t)pg;
        }
    }

    // gate tiles -> g_out[row][och] = sigmoid(h @ Wgate)
    for (int gt = 0; gt < 2; ++gt) {
        f32x4 acc = {0.f, 0.f, 0.f, 0.f};
        #pragma unroll
        for (int ks = 0; ks < 2; ++ks) {
            int kb = (ks * 32 + g * 8) * 2;
            int lr = 256 + gt * 16 + m;
            f16x8 bb = *(const f16x8*)((char*)Wl + lr * 128 + (kb ^ ((lr & 7) << 4)));
            acc = __builtin_amdgcn_mfma_f32_16x16x32_f16(af[ks], bb, acc, 0, 0, 0);
        }
        int och = ch * 32 + gt * 16 + m;
        #pragma unroll
        for (int r = 0; r < 4; ++r) {
            float og = 1.f / (1.f + __expf(-acc[r]));
            int grow = growbase + g * 4 + r;
            g_out[(size_t)grow * 64 + och] = (half_t)og;
        }
    }

    __syncthreads();
    // coalesced pg write-out: 128 channels x 64 rows (128B per channel row)
    #pragma unroll
    for (int it = 0; it < 4; ++it) {
        int chunk = it * 256 + t;          // 1024
        int c = chunk >> 3, r8 = chunk & 7;
        f16x8 v = *(const f16x8*)&pgl[c * 72 + r8 * 8];
        *(f16x8*)(dst + (size_t)c * ROWS + r0 + r8 * 8) = v;
    }
}

// ---------------------------------------------------------------- K3: batched einsum
// 512 blocks x 512 threads; 256x256 tile per block, XCD-grouped so a channel's
// 4 tiles land on one XCD's L2 (A/B half-panels each read twice -> L2 hit).
__global__ __launch_bounds__(512) void k_einsum(const half_t* __restrict__ a_t,
                                                const half_t* __restrict__ b_t,
                                                half_t* __restrict__ out_mid) {
    __shared__ half_t Al[256 * 64];   // 32 KB
    __shared__ half_t Bl[256 * 64];   // 32 KB

    int t = threadIdx.x;
    int bid = blockIdx.x;
    int xcd = bid & 7, kk = bid >> 3;
    int c = xcd + 8 * (kk >> 2);
    int tt = kk & 3;
    int i0 = (tt & 1) * 256, j0 = (tt >> 1) * 256;

    const half_t* A = a_t + (size_t)c * ROWS;   // [i][k]
    const half_t* B = b_t + (size_t)c * ROWS;   // [j][k]

    int wid = t >> 6, lane = t & 63;
    int m = lane & 15, g = lane >> 4;
    int wr = wid >> 2, wc = wid & 3;            // wave tile: 128 rows x 64 cols

    f32x4 acc[8][4] = {};

    for (int kt = 0; kt < 8; ++kt) {
        __syncthreads();
        #pragma unroll
        for (int rnd = 0; rnd < 4; ++rnd) {
            int chunk = rnd * 512 + t;          // 2048 per operand
            int row = chunk >> 3, slot = chunk & 7;
            uint4 va = *(const uint4*)(A + (size_t)(i0 + row) * 512 + kt * 64 + slot * 8);
            uint4 vb = *(const uint4*)(B + (size_t)(j0 + row) * 512 + kt * 64 + slot * 8);
            int boff = row * 128 + ((slot * 16) ^ ((row & 7) << 4));
            *(uint4*)((char*)Al + boff) = va;
            *(uint4*)((char*)Bl + boff) = vb;
        }
        __syncthreads();

        #pragma unroll
        for (int ks = 0; ks < 2; ++ks) {
            int kb = (ks * 32 + g * 8) * 2;
            f16x8 bf[4];
            #pragma unroll
            for (int ni = 0; ni < 4; ++ni) {
                int lrow = wc * 64 + ni * 16 + m;
                bf[ni] = *(const f16x8*)((char*)Bl + lrow * 128 + (kb ^ ((lrow & 7) << 4)));
            }
            #pragma unroll
            for (int mi = 0; mi < 8; ++mi) {
                int lrow = wr * 128 + mi * 16 + m;
                f16x8 af = *(const f16x8*)((char*)Al + lrow * 128 + (kb ^ ((lrow & 7) << 4)));
                #pragma unroll
                for (int ni = 0; ni < 4; ++ni)
                    acc[mi][ni] = __builtin_amdgcn_mfma_f32_16x16x32_f16(af, bf[ni], acc[mi][ni], 0, 0, 0);
            }
        }
    }

    half_t* O = out_mid + (size_t)c * ROWS;   // [i*512 + j]
    #pragma unroll
    for (int mi = 0; mi < 8; ++mi) {
        #pragma unroll
        for (int ni = 0; ni < 4; ++ni) {
            int row = i0 + wr * 128 + mi * 16 + g * 4;
            int col = j0 + wc * 64 + ni * 16 + m;
            #pragma unroll
            for (int r = 0; r < 4; ++r)
                O[(size_t)(row + r) * 512 + col] = (half_t)acc[mi][ni][r];
        }
    }
}

// ---------------------------------------------------------------- K4: folded LN + MFMA + gate
// out[p,o] = (rs_p*(x@W1)[o] - mu_p*rs_p*s1[o] + s2[o]) * gate[p,o]
__global__ __launch_bounds__(256) void k_final(const half_t* __restrict__ out_mid,
                                               const half_t* __restrict__ W1t,
                                               const float* __restrict__ s1g,
                                               const float* __restrict__ s2g,
                                               const half_t* __restrict__ g_out,
                                               float* __restrict__ out) {
    __shared__ half_t midl[128 * 64];   // [c][p] 16 KB linear
    __shared__ half_t midt[64 * 128];   // [p][c] 16 KB swizzled
    __shared__ half_t w1l[64 * 128];    // [o][c] 16 KB swizzled
    __shared__ half_t gl[64 * 72];      // [p][o] 9 KB padded
    __shared__ float smu[64], srs[64], s1l[64], s2l[64];

    int t = threadIdx.x;
    int pos0 = blockIdx.x * 64;

    #pragma unroll
    for (int it = 0; it < 4; ++it) {
        int chunk = it * 256 + t;       // 1024
        int cc = chunk >> 3, co = chunk & 7;
        *(uint4*)((char*)midl + cc * 128 + co * 16) =
            *(const uint4*)(out_mid + (size_t)cc * ROWS + pos0 + co * 8);
    }
    // w1l: 64 rows x 16 slots of 16B = 1024 chunks  (round-3 bug: was 512)
    #pragma unroll
    for (int it = 0; it < 4; ++it) {
        int chunk = it * 256 + t;       // 1024
        int row = chunk >> 4, slot = chunk & 15;
        *(uint4*)((char*)w1l + row * 256 + ((slot * 16) ^ ((row & 7) << 4))) =
            *(const uint4*)(W1t + row * 128 + slot * 8);
    }
    #pragma unroll
    for (int it = 0; it < 2; ++it) {
        int chunk = it * 256 + t;       // 512
        int row = chunk >> 3, co = chunk & 7;
        *(uint4*)((char*)gl + row * 144 + co * 16) =
            *(const uint4*)(g_out + (size_t)(pos0 + row) * 64 + co * 8);
    }
    if (t < 64) { s1l[t] = s1g[t]; s2l[t] = s2g[t]; }
    __syncthreads();

    // transpose midl -> midt (swizzled) + per-position stats
    {
        int p = t >> 2, q = t & 3;
        float s = 0.f, s2 = 0.f;
        #pragma unroll
        for (int cc4 = 0; cc4 < 4; ++cc4) {
            f16x8 pack;
            #pragma unroll
            for (int j = 0; j < 8; ++j) {
                half_t hv = midl[(q * 32 + cc4 * 8 + j) * 64 + p];
                float v = (float)hv;
                s += v; s2 += v * v;
                pack[j] = hv;
            }
            int slot = q * 4 + cc4;
            *(f16x8*)((char*)midt + p * 256 + ((slot * 16) ^ ((p & 7) << 4))) = pack;
        }
        s  += __shfl_xor(s, 1, 64);  s  += __shfl_xor(s, 2, 64);
        s2 += __shfl_xor(s2, 1, 64); s2 += __shfl_xor(s2, 2, 64);
        if (q == 0) {
            float mu = s * (1.f / 128.f);
            float var = s2 * (1.f / 128.f) - mu * mu;
            smu[p] = mu;
            srs[p] = rsqrtf(var + 1e-5f);
        }
    }
    __syncthreads();

    int wid = t >> 6, lane = t & 63;
    int m = lane & 15, g = lane >> 4;

    f32x4 acc[4] = {};
    #pragma unroll
    for (int ks = 0; ks < 4; ++ks) {
        int arow = wid * 16 + m;
        f16x8 af = *(const f16x8*)((char*)midt + arow * 256 +
                                   (((4 * ks + g) * 16) ^ ((arow & 7) << 4)));
        #pragma unroll
        for (int ni = 0; ni < 4; ++ni) {
            int brow = ni * 16 + m;
            f16x8 bf = *(const f16x8*)((char*)w1l + brow * 256 +
                                       (((4 * ks + g) * 16) ^ ((brow & 7) << 4)));
            acc[ni] = __builtin_amdgcn_mfma_f32_16x16x32_f16(af, bf, acc[ni], 0, 0, 0);
        }
    }

    #pragma unroll
    for (int ni = 0; ni < 4; ++ni) {
        int o = ni * 16 + m;
        float v1 = s1l[o], v2 = s2l[o];
        #pragma unroll
        for (int r = 0; r < 4; ++r) {
            int lrow = wid * 16 + g * 4 + r;
            float mu = smu[lrow], rs = srs[lrow];
            float val = acc[ni][r] * rs - mu * rs * v1 + v2;
            float gate = (float)gl[lrow * 72 + o];
            out[(size_t)(pos0 + lrow) * 64 + o] = val * gate;
        }
    }
}

// ---------------------------------------------------------------- launch
extern "C" void kernel_launch(void* const* d_in, const int* in_sizes, int n_in,
                              void* d_out, int out_size, void* d_ws, size_t ws_size,
                              hipStream_t stream) {
    const float* z        = (const float*)d_in[0];
    const float* ln_in_w  = (const float*)d_in[1];
    const float* ln_in_b  = (const float*)d_in[2];
    const float* Wp       = (const float*)d_in[3];
    const float* Wg       = (const float*)d_in[4];
    const float* ln_out_w = (const float*)d_in[5];
    const float* ln_out_b = (const float*)d_in[6];
    const float* Wout     = (const float*)d_in[7];
    const float* Wgate    = (const float*)d_in[8];
    float* out = (float*)d_out;

    // ws layout (235,012,096 B total < 256 MiB):
    //   [0, 128K)    Wt(73728) | W1t@81920(16384) | s1@98304(256) | s2@98560(256)
    //   [128K,+67MB) a_t ; +67MB b_t ; +33.5MB gout ; +67MB omid (h aliases omid)
    char* wsb = (char*)d_ws;
    half_t* Wt   = (half_t*)wsb;
    half_t* W1t  = (half_t*)(wsb + 81920);
    float*  s1   = (float*)(wsb + 98304);
    float*  s2   = (float*)(wsb + 98560);
    half_t* a_t  = (half_t*)(wsb + 131072);
    half_t* b_t  = a_t + (size_t)HID * ROWS;
    half_t* gout = b_t + (size_t)HID * ROWS;
    half_t* omid = gout + (size_t)ROWS * 64;
    half_t* h    = omid;   // aliased: h consumed by K2, omid produced by K3

    k_prep_w<<<dim3(145), dim3(256), 0, stream>>>(Wp, Wg, Wgate, ln_out_w, ln_out_b, Wout,
                                                  Wt, W1t, s1, s2);
    k_ln_in<<<dim3(ROWS / 4), dim3(256), 0, stream>>>(z, ln_in_w, ln_in_b, h);
    k_proj<<<dim3(ROWS / 64, 2), dim3(256), 0, stream>>>(h, Wt, a_t, b_t, gout);
    k_einsum<<<dim3(512), dim3(512), 0, stream>>>(a_t, b_t, omid);
    k_final<<<dim3(ROWS / 64), dim3(256), 0, stream>>>(omid, W1t, s1, s2, gout, out);
}